// Round 1
// baseline (185.030 us; speedup 1.0000x reference)
//
#include <hip/hip_runtime.h>

constexpr int   NUM_CLASSES  = 10;
constexpr float LAMBDA_COORD = 5.0f;
constexpr float LAMBDA_NOOBJ = 0.5f;
constexpr int   BLOCK = 256;
// 20,766,720 floats = 5,191,680 float4 = 2028 blocks * 256 threads * 10 slots exactly
constexpr int   NBLOCKS_MAX = 2028;
constexpr int   UNROLL = 5;

// Per-float4-slot processing. Element position j = j0+m within (up to) two
// cells; second cell (j>=15) elements always have jj = j-15 <= 2 -> always
// coord candidates. The conf element (jj==4) can only live in the first
// cell (j0+3 <= 17 < 19), exists iff j0 in [1,4] at m = 4-j0, and its
// target/obj flag is t4a. Bucket masks collapse to single unsigned cmps:
//   coord: j<4 || j>=15  <=>  (j-4u)  >= 11u
//   cls:   5<=j<=14      <=>  (j-5u)  <  10u
__device__ __forceinline__ void slot(const float4 p, const float4 t,
                                     const float t4a, const float t4b,
                                     unsigned j0,
                                     float& coord, float& conf, float& cls)
{
    const float pm[4] = {p.x, p.y, p.z, p.w};
    const float tm[4] = {t.x, t.y, t.z, t.w};

#pragma unroll
    for (int m = 0; m < 4; ++m) {
        unsigned j  = j0 + (unsigned)m;
        float d     = pm[m] - tm[m];
        float sq    = d * d;
        float t4    = (j >= 15u) ? t4b : t4a;
        float sqo   = (t4 > 0.f) ? sq : 0.f;
        coord += ((j - 4u) >= 11u) ? sqo : 0.f;
        cls   += ((j - 5u) <  10u) ? sqo : 0.f;
    }

    // one sigmoid per slot, on the (unique) conf element if present
    bool  hasConf = (j0 - 1u) < 4u;            // j0 in [1,4]
    float pc = (j0 == 4u) ? pm[0]
             : (j0 == 3u) ? pm[1]
             : (j0 == 2u) ? pm[2]
             :              pm[3];              // j0==1 -> m=3
    float e   = __expf(-pc);
    float sig = 1.f / (1.f + e);                // precise div, 1x per slot
    bool  obj = t4a > 0.f;
    float dsv = sig - t4a;                      // conf target == t4a
    float confv = obj ? dsv * dsv : LAMBDA_NOOBJ * sig * sig;
    conf += hasConf ? confv : 0.f;
}

__global__ __launch_bounds__(BLOCK) void yolo_main(
    const float4* __restrict__ pred4,
    const float4* __restrict__ tgt4,
    const float*  __restrict__ tgt,
    float* __restrict__ ws,
    unsigned n4, unsigned nblocks)
{
    unsigned idx    = blockIdx.x * BLOCK + threadIdx.x;
    unsigned stride = nblocks * BLOCK;

    float coord = 0.f, conf = 0.f, cls = 0.f;

    unsigned k = idx;
    // main loop: UNROLL slots per iteration, load-phase then compute-phase
    // (20 independent loads in flight per wave)
    for (; k + (UNROLL - 1) * stride < n4; k += UNROLL * stride) {
        float4   p[UNROLL], t[UNROLL];
        float    ta[UNROLL], tb[UNROLL];
        unsigned j0s[UNROLL];

#pragma unroll
        for (int u = 0; u < UNROLL; ++u) {
            unsigned kk    = k + (unsigned)u * stride;
            p[u]           = pred4[kk];
            t[u]           = tgt4[kk];
            unsigned base  = 4u * kk;
            unsigned cell0 = base / 15u;          // magic-mul
            unsigned c15   = cell0 * 15u;
            unsigned j0    = base - c15;
            j0s[u]         = j0;
            ta[u]          = tgt[c15 + 4u];
            // crossing into next cell only if j0 >= 12; else alias t4a (L1 hit)
            tb[u]          = tgt[(j0 >= 12u) ? c15 + 19u : c15 + 4u];
        }

#pragma unroll
        for (int u = 0; u < UNROLL; ++u)
            slot(p[u], t[u], ta[u], tb[u], j0s[u], coord, conf, cls);
    }

    // tail (never executes for the exact 2028-block partition)
    for (; k < n4; k += stride) {
        float4 p = pred4[k];
        float4 t = tgt4[k];
        unsigned base  = 4u * k;
        unsigned cell0 = base / 15u;
        unsigned c15   = cell0 * 15u;
        unsigned j0    = base - c15;
        float ta = tgt[c15 + 4u];
        float tb = tgt[(j0 >= 12u) ? c15 + 19u : c15 + 4u];
        slot(p, t, ta, tb, j0, coord, conf, cls);
    }

    // wave64 shuffle reduce
#pragma unroll
    for (int off = 32; off > 0; off >>= 1) {
        coord += __shfl_down(coord, off);
        conf  += __shfl_down(conf,  off);
        cls   += __shfl_down(cls,   off);
    }

    __shared__ float s[3][4];
    int wave = threadIdx.x >> 6, lane = threadIdx.x & 63;
    if (lane == 0) { s[0][wave] = coord; s[1][wave] = conf; s[2][wave] = cls; }
    __syncthreads();

    if (threadIdx.x == 0) {
        float c0 = s[0][0] + s[0][1] + s[0][2] + s[0][3];
        float c1 = s[1][0] + s[1][1] + s[1][2] + s[1][3];
        float c2 = s[2][0] + s[2][1] + s[2][2] + s[2][3];
        ws[blockIdx.x]               = c0;
        ws[nblocks + blockIdx.x]     = c1;
        ws[2 * nblocks + blockIdx.x] = c2;
    }
}

__global__ __launch_bounds__(BLOCK) void yolo_finalize(
    const float* __restrict__ ws, float* __restrict__ out, unsigned nblocks)
{
    float c0 = 0.f, c1 = 0.f, c2 = 0.f;
    for (unsigned i = threadIdx.x; i < nblocks; i += BLOCK) {
        c0 += ws[i];
        c1 += ws[nblocks + i];
        c2 += ws[2 * nblocks + i];
    }
#pragma unroll
    for (int off = 32; off > 0; off >>= 1) {
        c0 += __shfl_down(c0, off);
        c1 += __shfl_down(c1, off);
        c2 += __shfl_down(c2, off);
    }
    __shared__ float s[3][4];
    int wave = threadIdx.x >> 6, lane = threadIdx.x & 63;
    if (lane == 0) { s[0][wave] = c0; s[1][wave] = c1; s[2][wave] = c2; }
    __syncthreads();
    if (threadIdx.x == 0) {
        float coord = LAMBDA_COORD * (s[0][0] + s[0][1] + s[0][2] + s[0][3]);
        float conf  =                 s[1][0] + s[1][1] + s[1][2] + s[1][3];
        float cls   = (1.f / NUM_CLASSES) * (s[2][0] + s[2][1] + s[2][2] + s[2][3]);
        out[0] = coord + conf + cls;
        out[1] = coord;
        out[2] = conf;
        out[3] = cls;
    }
}

extern "C" void kernel_launch(void* const* d_in, const int* in_sizes, int n_in,
                              void* d_out, int out_size, void* d_ws, size_t ws_size,
                              hipStream_t stream) {
    const float* pred = (const float*)d_in[0];
    const float* tgt  = (const float*)d_in[1];
    float* out = (float*)d_out;
    float* ws  = (float*)d_ws;

    unsigned total = (unsigned)in_sizes[0];   // B*S*S*15 = 20,766,720 (div by 4)
    unsigned n4    = total / 4u;

    unsigned nblocks = NBLOCKS_MAX;
    size_t need = (size_t)nblocks * 3 * sizeof(float);
    if (need > ws_size) nblocks = (unsigned)(ws_size / (3 * sizeof(float)));

    yolo_main<<<nblocks, BLOCK, 0, stream>>>(
        (const float4*)pred, (const float4*)tgt, tgt, ws, n4, nblocks);
    yolo_finalize<<<1, BLOCK, 0, stream>>>(ws, out, nblocks);
}